// Round 7
// baseline (1304.216 us; speedup 1.0000x reference)
//
#include <hip/hip_runtime.h>
#include <math.h>

#define LL 256
#define BB 128
#define EDIM 1024
#define HDIM 1024
#define VOCAB 32000

#define NKSF 8    // fhid K-splits (K=128 per block, 2 chunks of 64)
#define NKS  16   // part K-splits (K=256 per block, 4 chunks of 64)

// workspace layout (float offsets)
#define WS_EACT   0        // 32000
#define WS_ACC    32512    // 16 floats: [0..3] finals sums, [4] finals cnt,
                           //            [5] fhid_done, [6] eact_done
#define WS_FHID   33024    // 262144
#define WS_BIG    295168   // fpart (8*256*1024) then reused as part (16*128*1024)

#define APAD 68   // LDS staging row stride (R0/R4-proven)

#define NEACT 8000   // eact blocks in L1

__device__ __forceinline__ void fma4(float4& a, float s, const float4& w) {
  a.x = fmaf(s, w.x, a.x); a.y = fmaf(s, w.y, a.y);
  a.z = fmaf(s, w.z, a.z); a.w = fmaf(s, w.w, a.w);
}

// L1: blocks 0..255    = fhid K-split partials (R0-proven), signal cnt[5];
//     blocks 256..8255 = E_act stream (R0-proven), signal cnt[6];
//     blocks 8256..8511 = tanh tail: spin cnt[5]==256, then fhid=tanh(sum+b);
//     blocks 8512..8767 = stats tail: spin cnt[6]==NEACT, then ragged stats +
//                         atomic finals into out[384..387] (R6-proven pattern).
// Deadlock-free: 512 tail blocks < residency capacity (4 blk/CU * 256 CU),
// so producer blocks always have slots regardless of dispatch order.
extern "C" __global__ __launch_bounds__(256)
void k_l1(const float* __restrict__ emb, const float* __restrict__ Wtop,
          const float* __restrict__ Wact,
          const int* __restrict__ seq1, const int* __restrict__ seq2,
          const float* __restrict__ btop, const float* __restrict__ b_act,
          float* __restrict__ fpart, float* __restrict__ Eact,
          float* __restrict__ fhid, float* __restrict__ accbuf,
          float* __restrict__ out) {
  __shared__ float ash[128 * APAD];
  __shared__ int stok[128];
  int blk = blockIdx.x, tid = threadIdx.x;
  int* fhid_done = (int*)(accbuf + 5);
  int* eact_done = (int*)(accbuf + 6);

  if (blk >= 8512) {
    // ---- stats tail for (s,b): needs all Eact ----
    if (tid == 0) {
      while (atomicAdd(eact_done, 0) < NEACT) __builtin_amdgcn_s_sleep(32);
    }
    __syncthreads();
    int sb = blk - 8512;
    int s = sb >> 7, b = sb & 127;
    const int* seq = s ? seq2 : seq1;
    int* col = (int*)ash;            // [256]
    int* zred = (int*)ash + 256;     // [256]
    float* redf = ash + 512;         // [256]
    int v = seq[tid * BB + b];
    col[tid] = v;
    zred[tid] = (v == 0) ? 1 : 0;
    __syncthreads();
    for (int off = 128; off; off >>= 1) {
      if (tid < off) zred[tid] += zred[tid + off];
      __syncthreads();
    }
    int lens = LL - zred[0] - 1;
    int Ts = 2 * lens - 1;
    float ba = b_act[0] - b_act[1];
    float sp = 0.f, sq = 0.f;
    for (int t = tid; t < Ts; t += 256) {
      int tok = (t < LL) ? col[t] : col[t - LL];
      float d = Eact[tok] + ba;
      float p0 = 1.0f / (1.0f + expf(-d));
      float dd = 2.f * p0 - 1.f;   // push - pop
      sp += dd;
      sq = fmaf(dd, dd, sq);
    }
    redf[tid] = sp; __syncthreads();
    for (int off = 128; off; off >>= 1) { if (tid < off) redf[tid] += redf[tid + off]; __syncthreads(); }
    float tsp = redf[0]; __syncthreads();
    redf[tid] = sq; __syncthreads();
    for (int off = 128; off; off >>= 1) { if (tid < off) redf[tid] += redf[tid + off]; __syncthreads(); }
    if (tid == 0) {
      float Tf = (float)Ts;
      float delta = (tsp - 1.0f) / Tf;
      float dfb = sqrtf(redf[0]) / Tf;
      atomicAdd(&accbuf[s], delta * delta);
      atomicAdd(&accbuf[2 + s], dfb);
      __threadfence();
      int old = atomicAdd((int*)(accbuf + 4), 1);
      if (old == 255) {
        __threadfence();
        float d0 = atomicAdd(&accbuf[0], 0.f);
        float d1 = atomicAdd(&accbuf[1], 0.f);
        float f0 = atomicAdd(&accbuf[2], 0.f);
        float f1 = atomicAdd(&accbuf[3], 0.f);
        out[384] = sqrtf(d0) / (float)BB;
        out[385] = sqrtf(d1) / (float)BB;
        out[386] = f0 / (float)BB;
        out[387] = f1 / (float)BB;
      }
    }
    return;
  }
  if (blk >= 8256) {
    // ---- tanh tail: fhid = tanh(sum_ks fpart + b_top) ----
    if (tid == 0) {
      while (atomicAdd(fhid_done, 0) < 256) __builtin_amdgcn_s_sleep(32);
    }
    __syncthreads();
    int g = (blk - 8256) * 256 + tid;   // 65536 float4s
    float4 s = ((const float4*)fpart)[g];
#pragma unroll
    for (int k = 1; k < NKSF; ++k) {
      float4 p = ((const float4*)fpart)[(size_t)k * 65536 + g];
      s.x += p.x; s.y += p.y; s.z += p.z; s.w += p.w;
    }
    float4 b = ((const float4*)btop)[g & 255];
    ((float4*)fhid)[g] = make_float4(tanhf(s.x + b.x), tanhf(s.y + b.y),
                                     tanhf(s.z + b.z), tanhf(s.w + b.w));
    return;
  }
  if (blk >= 256) {
    // ---- E_act: one vocab row per wave, single channel (w0 - w1) ----
    int lane = tid & 63, wave = tid >> 6;
    int v = (blk - 256) * 4 + wave;
    const float4* row = (const float4*)(emb + (size_t)v * EDIM);
    const float4* w4 = (const float4*)Wact;   // [e][2] interleaved
    float a0 = 0.f;
#pragma unroll
    for (int it = 0; it < 4; ++it) {
      int i = lane + it * 64;
      float4 x = row[i];
      float4 wa = w4[2 * i];
      float4 wb = w4[2 * i + 1];
      a0 = fmaf(x.x, wa.x - wa.y, a0);
      a0 = fmaf(x.y, wa.z - wa.w, a0);
      a0 = fmaf(x.z, wb.x - wb.y, a0);
      a0 = fmaf(x.w, wb.z - wb.w, a0);
    }
#pragma unroll
    for (int off = 32; off; off >>= 1)
      a0 += __shfl_down(a0, off, 64);
    if (lane == 0) Eact[v] = a0;
    __threadfence();
    __syncthreads();
    if (tid == 0) atomicAdd(eact_done, 1);
    return;
  }
  // ---- fhid partial: ks = blk>>5 (8), rb = (blk>>4)&1, cb = blk&15 ; K=128 ----
  int ks = blk >> 5, rb = (blk >> 4) & 1, cb = blk & 15;
  int cg = tid & 15, rgr = tid >> 4;
  int c0 = cb * 64 + cg * 4;
  int kbase = ks * 128;
  const int* seq = rb ? seq2 : seq1;
  // self-compute final tokens for this rb half: 2 threads per batch column
  {
    int c = tid >> 1, h = tid & 1;
    int z = 0;
    int base = h * 128;
    for (int r = 0; r < 128; ++r)
      z += (seq[(base + r) * BB + c] == 0) ? 1 : 0;
    z += __shfl_xor(z, 1, 64);
    if (h == 0) {
      int lens = 255 - z;           // L - pads - 1
      int tt = 2 * lens - 2;        // Ts - 1
      int idx = (tt < LL) ? tt : tt - LL;
      stok[c] = seq[idx * BB + c];
    }
  }
  float4 acc[8];
#pragma unroll
  for (int r = 0; r < 8; ++r) acc[r] = make_float4(0.f, 0.f, 0.f, 0.f);
#pragma unroll
  for (int ch = 0; ch < 2; ++ch) {
    int kg = kbase + ch * 64;
    __syncthreads();                 // covers stok on first pass
    for (int idx = tid; idx < 128 * 16; idx += 256) {
      int r = idx >> 4, q = idx & 15;
      *(float4*)&ash[r * APAD + q * 4] =
          ((const float4*)(emb + (size_t)stok[r] * EDIM + kg))[q];
    }
    __syncthreads();
    const float* Wp = Wtop + (size_t)kg * HDIM + c0;
    float4 w[4];
#pragma unroll
    for (int j = 0; j < 4; ++j) w[j] = *(const float4*)(Wp + (size_t)j * HDIM);
#pragma unroll
    for (int kk = 0; kk < 64; kk += 4) {
      float4 wn[4];
      if (kk + 4 < 64) {
#pragma unroll
        for (int j = 0; j < 4; ++j) wn[j] = *(const float4*)(Wp + (size_t)(kk + 4 + j) * HDIM);
      }
#pragma unroll
      for (int r = 0; r < 8; ++r) {
        float4 a = *(const float4*)&ash[(rgr * 8 + r) * APAD + kk];
        fma4(acc[r], a.x, w[0]); fma4(acc[r], a.y, w[1]);
        fma4(acc[r], a.z, w[2]); fma4(acc[r], a.w, w[3]);
      }
#pragma unroll
      for (int j = 0; j < 4; ++j) w[j] = wn[j];
    }
  }
  float* dst = fpart + ((size_t)ks * 256 + rb * 128 + rgr * 8) * HDIM + c0;
#pragma unroll
  for (int r = 0; r < 8; ++r)
    *(float4*)(dst + (size_t)r * HDIM) = acc[r];
  __threadfence();
  __syncthreads();
  if (tid == 0) atomicAdd(fhid_done, 1);
}

// L2: u@W1 K-split partials; 512 blocks = ksb(16) x cb(16) x rh(2), K=256,
//     64 batch rows per block (4 strided rows/thread).  [R4-proven code]
extern "C" __global__ __launch_bounds__(256)
void k_part(const float* __restrict__ fhid, const float* __restrict__ W1,
            float* __restrict__ part) {
  __shared__ float ush[64 * APAD];
  int blk = blockIdx.x, tid = threadIdx.x;
  int g = blk >> 1, rh = blk & 1;
  int ksb = g >> 4, cb = g & 15;
  int cg = tid & 15, rgr = tid >> 4;
  int c0 = cb * 64 + cg * 4;
  int m0 = rh * 64;
  int seg = ksb >> 2;                 // constant per block
  const float4* f4 = (const float4*)fhid;
  float4 acc[4];
#pragma unroll
  for (int r = 0; r < 4; ++r) acc[r] = make_float4(0.f, 0.f, 0.f, 0.f);
  for (int kch = 0; kch < 4; ++kch) {
    int kg = ksb * 256 + kch * 64;
    int fb4 = (kg & 1023) >> 2;
    __syncthreads();
#pragma unroll
    for (int j = 0; j < 4; ++j) {
      int idx = tid + j * 256;           // 0..1023
      int r = idx >> 4, q = idx & 15;    // r 0..63
      int row = m0 + r;
      float4 uv;
      if (seg == 0) uv = f4[row * 256 + fb4 + q];
      else if (seg == 1) uv = f4[(128 + row) * 256 + fb4 + q];
      else {
        float4 f1v = f4[row * 256 + fb4 + q];
        float4 f2v = f4[(128 + row) * 256 + fb4 + q];
        if (seg == 2)
          uv = make_float4(fabsf(f1v.x - f2v.x), fabsf(f1v.y - f2v.y),
                           fabsf(f1v.z - f2v.z), fabsf(f1v.w - f2v.w));
        else
          uv = make_float4(f1v.x * f2v.x, f1v.y * f2v.y,
                           f1v.z * f2v.z, f1v.w * f2v.w);
      }
      *(float4*)&ush[r * APAD + q * 4] = uv;
    }
    __syncthreads();
    const float* Wp = W1 + (size_t)kg * HDIM + c0;
    float4 w[4];
#pragma unroll
    for (int j = 0; j < 4; ++j) w[j] = *(const float4*)(Wp + (size_t)j * HDIM);
#pragma unroll
    for (int kk = 0; kk < 64; kk += 4) {
      float4 wn[4];
      if (kk + 4 < 64) {
#pragma unroll
        for (int j = 0; j < 4; ++j)
          wn[j] = *(const float4*)(Wp + (size_t)(kk + 4 + j) * HDIM);
      }
#pragma unroll
      for (int r = 0; r < 4; ++r) {
        float4 a = *(const float4*)&ush[(rgr + 16 * r) * APAD + kk];
        fma4(acc[r], a.x, w[0]); fma4(acc[r], a.y, w[1]);
        fma4(acc[r], a.z, w[2]); fma4(acc[r], a.w, w[3]);
      }
#pragma unroll
      for (int j = 0; j < 4; ++j) w[j] = wn[j];
    }
  }
  float* dst = part + ((size_t)ksb * 128 + m0 + rgr) * HDIM + c0;
#pragma unroll
  for (int r = 0; r < 4; ++r)
    *(float4*)(dst + (size_t)r * 16 * HDIM) = acc[r];
}

// L3: 128 blocks = classifier for batch b (NKS=16 float4 reduce, direct store).
//     (dis/diff finals already written by L1's stats tail.)
extern "C" __global__ __launch_bounds__(256)
void k_clf(const float* __restrict__ part, const float* __restrict__ b1,
           const float* __restrict__ W2, const float* __restrict__ b2,
           float* __restrict__ out) {
  int blk = blockIdx.x, tid = threadIdx.x;
  __shared__ float red[768];
  int b = blk;
  float4 p = ((const float4*)b1)[tid];
  const float4* p4 = (const float4*)part;
#pragma unroll
  for (int ks = 0; ks < NKS; ++ks) {
    float4 q = p4[((size_t)ks * 128 + b) * 256 + tid];
    p.x += q.x; p.y += q.y; p.z += q.z; p.w += q.w;
  }
  p.x = fmaxf(p.x, 0.f); p.y = fmaxf(p.y, 0.f);
  p.z = fmaxf(p.z, 0.f); p.w = fmaxf(p.w, 0.f);
  int k0 = tid * 4;
  float a0 = 0.f, a1 = 0.f, a2 = 0.f;
  a0 = fmaf(p.x, W2[(k0 + 0) * 3 + 0], a0); a1 = fmaf(p.x, W2[(k0 + 0) * 3 + 1], a1); a2 = fmaf(p.x, W2[(k0 + 0) * 3 + 2], a2);
  a0 = fmaf(p.y, W2[(k0 + 1) * 3 + 0], a0); a1 = fmaf(p.y, W2[(k0 + 1) * 3 + 1], a1); a2 = fmaf(p.y, W2[(k0 + 1) * 3 + 2], a2);
  a0 = fmaf(p.z, W2[(k0 + 2) * 3 + 0], a0); a1 = fmaf(p.z, W2[(k0 + 2) * 3 + 1], a1); a2 = fmaf(p.z, W2[(k0 + 2) * 3 + 2], a2);
  a0 = fmaf(p.w, W2[(k0 + 3) * 3 + 0], a0); a1 = fmaf(p.w, W2[(k0 + 3) * 3 + 1], a1); a2 = fmaf(p.w, W2[(k0 + 3) * 3 + 2], a2);
  red[tid] = a0; red[256 + tid] = a1; red[512 + tid] = a2;
  __syncthreads();
  for (int off = 128; off; off >>= 1) {
    if (tid < off) {
      red[tid] += red[tid + off];
      red[256 + tid] += red[256 + tid + off];
      red[512 + tid] += red[512 + tid + off];
    }
    __syncthreads();
  }
  if (tid == 0) {
    out[b * 3 + 0] = red[0]   + b2[0];
    out[b * 3 + 1] = red[256] + b2[1];
    out[b * 3 + 2] = red[512] + b2[2];
  }
}

extern "C" void kernel_launch(void* const* d_in, const int* in_sizes, int n_in,
                              void* d_out, int out_size, void* d_ws, size_t ws_size,
                              hipStream_t stream) {
  const int*   seq1  = (const int*)  d_in[0];
  const int*   seq2  = (const int*)  d_in[1];
  const float* emb   = (const float*)d_in[2];
  const float* W_top = (const float*)d_in[3];
  const float* b_top = (const float*)d_in[4];
  const float* W_act = (const float*)d_in[5];
  const float* b_act = (const float*)d_in[6];
  const float* W1    = (const float*)d_in[7];
  const float* b1    = (const float*)d_in[8];
  const float* W2    = (const float*)d_in[9];
  const float* b2    = (const float*)d_in[10];
  float* out = (float*)d_out;
  float* ws  = (float*)d_ws;

  float* Eact  = ws + WS_EACT;
  float* accb  = ws + WS_ACC;
  float* fhid  = ws + WS_FHID;
  float* bigb  = ws + WS_BIG;   // fpart, then reused as part

  hipMemsetAsync(accb, 0, 64, stream);   // zero counters + finals accumulators
  hipLaunchKernelGGL(k_l1,   dim3(256 + NEACT + 512), dim3(256), 0, stream,
                     emb, W_top, W_act, seq1, seq2, b_top, b_act,
                     bigb, Eact, fhid, accb, out);
  hipLaunchKernelGGL(k_part, dim3(512), dim3(256), 0, stream, fhid, W1, bigb);
  hipLaunchKernelGGL(k_clf,  dim3(128), dim3(256), 0, stream, bigb, b1, W2, b2, out);
}

// Round 8
// 259.025 us; speedup vs baseline: 5.0351x; 5.0351x over previous
//
#include <hip/hip_runtime.h>
#include <math.h>

#define LL 256
#define BB 128
#define EDIM 1024
#define HDIM 1024
#define VOCAB 32000

#define NKSF 8    // fhid K-splits (K=128 per block, 2 chunks of 64)  [round-0 proven]
#define NKS  16   // part K-splits (K=256 per block, 4 chunks of 64)

// workspace layout (float offsets)
#define WS_EACT   0        // 32000 (single channel: emb . (w0-w1))
#define WS_DELTA  32000    // 256
#define WS_DIFFB  32256    // 256
#define WS_FHID   33024    // 262144
#define WS_BIG    295168   // fpart (8*256*1024=2.1M) then reused as part (16*128*1024=2.1M)

#define APAD 68   // LDS staging row stride (16B-aligned)

__device__ __forceinline__ void fma4(float4& a, float s, const float4& w) {
  a.x = fmaf(s, w.x, a.x); a.y = fmaf(s, w.y, a.y);
  a.z = fmaf(s, w.z, a.z); a.w = fmaf(s, w.w, a.w);
}

// K_B: blocks 0..255 = fhid K-split partials (self-compute final tokens);
//      blocks 256..8255 = E_act stream.  [byte-identical to round-0 proven 259.7]
extern "C" __global__ __launch_bounds__(256)
void k_fh_eact(const float* __restrict__ emb, const float* __restrict__ Wtop,
               const float* __restrict__ Wact,
               const int* __restrict__ seq1, const int* __restrict__ seq2,
               float* __restrict__ fpart, float* __restrict__ Eact) {
  __shared__ float ash[128 * APAD];
  __shared__ int stok[128];
  int blk = blockIdx.x, tid = threadIdx.x;
  if (blk >= 256) {
    // ---- E_act: one vocab row per wave, single channel (w0 - w1) ----
    int lane = tid & 63, wave = tid >> 6;
    int v = (blk - 256) * 4 + wave;
    const float4* row = (const float4*)(emb + (size_t)v * EDIM);
    const float4* w4 = (const float4*)Wact;   // [e][2] interleaved
    float a0 = 0.f;
#pragma unroll
    for (int it = 0; it < 4; ++it) {
      int i = lane + it * 64;
      float4 x = row[i];
      float4 wa = w4[2 * i];
      float4 wb = w4[2 * i + 1];
      a0 = fmaf(x.x, wa.x - wa.y, a0);
      a0 = fmaf(x.y, wa.z - wa.w, a0);
      a0 = fmaf(x.z, wb.x - wb.y, a0);
      a0 = fmaf(x.w, wb.z - wb.w, a0);
    }
#pragma unroll
    for (int off = 32; off; off >>= 1)
      a0 += __shfl_down(a0, off, 64);
    if (lane == 0) Eact[v] = a0;
    return;
  }
  // ---- fhid partial: ks = blk>>5 (8), rb = (blk>>4)&1, cb = blk&15 ; K=128 ----
  int ks = blk >> 5, rb = (blk >> 4) & 1, cb = blk & 15;
  int cg = tid & 15, rgr = tid >> 4;
  int c0 = cb * 64 + cg * 4;
  int kbase = ks * 128;
  const int* seq = rb ? seq2 : seq1;
  // self-compute final tokens for this rb half: 2 threads per batch column
  {
    int c = tid >> 1, h = tid & 1;
    int z = 0;
    int base = h * 128;
    for (int r = 0; r < 128; ++r)
      z += (seq[(base + r) * BB + c] == 0) ? 1 : 0;
    z += __shfl_xor(z, 1, 64);
    if (h == 0) {
      int lens = 255 - z;           // L - pads - 1
      int tt = 2 * lens - 2;        // Ts - 1
      int idx = (tt < LL) ? tt : tt - LL;
      stok[c] = seq[idx * BB + c];
    }
  }
  float4 acc[8];
#pragma unroll
  for (int r = 0; r < 8; ++r) acc[r] = make_float4(0.f, 0.f, 0.f, 0.f);
#pragma unroll
  for (int ch = 0; ch < 2; ++ch) {
    int kg = kbase + ch * 64;
    __syncthreads();
    for (int idx = tid; idx < 128 * 16; idx += 256) {
      int r = idx >> 4, q = idx & 15;
      *(float4*)&ash[r * APAD + q * 4] =
          ((const float4*)(emb + (size_t)stok[r] * EDIM + kg))[q];
    }
    __syncthreads();
    const float* Wp = Wtop + (size_t)kg * HDIM + c0;
    float4 w[4];
#pragma unroll
    for (int j = 0; j < 4; ++j) w[j] = *(const float4*)(Wp + (size_t)j * HDIM);
#pragma unroll
    for (int kk = 0; kk < 64; kk += 4) {
      float4 wn[4];
      if (kk + 4 < 64) {
#pragma unroll
        for (int j = 0; j < 4; ++j) wn[j] = *(const float4*)(Wp + (size_t)(kk + 4 + j) * HDIM);
      }
#pragma unroll
      for (int r = 0; r < 8; ++r) {
        float4 a = *(const float4*)&ash[(rgr * 8 + r) * APAD + kk];
        fma4(acc[r], a.x, w[0]); fma4(acc[r], a.y, w[1]);
        fma4(acc[r], a.z, w[2]); fma4(acc[r], a.w, w[3]);
      }
#pragma unroll
      for (int j = 0; j < 4; ++j) w[j] = wn[j];
    }
  }
  float* dst = fpart + ((size_t)ks * 256 + rb * 128 + rgr * 8) * HDIM + c0;
#pragma unroll
  for (int r = 0; r < 8; ++r)
    *(float4*)(dst + (size_t)r * HDIM) = acc[r];
}

// K_C: blocks 0..255 = fhid = tanh(sum_ks fpart + b_top);
//      blocks 256..511 = ragged softmax stats.  [byte-identical to round-0]
extern "C" __global__ __launch_bounds__(256)
void k_ftanh_stats(const float* __restrict__ fpart, const float* __restrict__ btop,
                   const int* __restrict__ seq1, const int* __restrict__ seq2,
                   const float* __restrict__ Eact, const float* __restrict__ b_act,
                   float* __restrict__ fhid, float* __restrict__ delta,
                   float* __restrict__ diffb) {
  int blk = blockIdx.x, tid = threadIdx.x;
  if (blk < 256) {
    int g = blk * 256 + tid;   // 65536 float4s
    float4 s = ((const float4*)fpart)[g];
#pragma unroll
    for (int k = 1; k < NKSF; ++k) {
      float4 p = ((const float4*)fpart)[(size_t)k * 65536 + g];
      s.x += p.x; s.y += p.y; s.z += p.z; s.w += p.w;
    }
    float4 b = ((const float4*)btop)[g & 255];
    ((float4*)fhid)[g] = make_float4(tanhf(s.x + b.x), tanhf(s.y + b.y),
                                     tanhf(s.z + b.z), tanhf(s.w + b.w));
    return;
  }
  // ---- stats for (s,b) ----
  int sb = blk - 256;
  int s = sb >> 7, b = sb & 127;
  const int* seq = s ? seq2 : seq1;
  __shared__ int col[LL];
  __shared__ int zred[256];
  __shared__ float redf[256];
  int v = seq[tid * BB + b];
  col[tid] = v;
  zred[tid] = (v == 0) ? 1 : 0;
  __syncthreads();
  for (int off = 128; off; off >>= 1) {
    if (tid < off) zred[tid] += zred[tid + off];
    __syncthreads();
  }
  int lens = LL - zred[0] - 1;
  int Ts = 2 * lens - 1;
  float ba = b_act[0] - b_act[1];
  float sp = 0.f, sq = 0.f;
  for (int t = tid; t < Ts; t += 256) {
    int tok = (t < LL) ? col[t] : col[t - LL];
    float d = Eact[tok] + ba;
    float p0 = 1.0f / (1.0f + expf(-d));
    float dd = 2.f * p0 - 1.f;   // push - pop
    sp += dd;
    sq = fmaf(dd, dd, sq);
  }
  redf[tid] = sp; __syncthreads();
  for (int off = 128; off; off >>= 1) { if (tid < off) redf[tid] += redf[tid + off]; __syncthreads(); }
  float tsp = redf[0]; __syncthreads();
  redf[tid] = sq; __syncthreads();
  for (int off = 128; off; off >>= 1) { if (tid < off) redf[tid] += redf[tid + off]; __syncthreads(); }
  if (tid == 0) {
    float Tf = (float)Ts;
    delta[sb] = (tsp - 1.0f) / Tf;
    diffb[sb] = sqrtf(redf[0]) / Tf;
  }
}

// K_D: u@W1 K-split partials; 512 blocks = ksb(16) x cb(16) x rh(2), K=256,
//      64 batch rows per block (4 strided rows/thread), part = 16 splits.
//      Strided row ownership (rgr+16j): conflict-free ds_read_b128.
extern "C" __global__ __launch_bounds__(256)
void k_part(const float* __restrict__ fhid, const float* __restrict__ W1,
            float* __restrict__ part) {
  __shared__ float ush[64 * APAD];
  int blk = blockIdx.x, tid = threadIdx.x;
  int g = blk >> 1, rh = blk & 1;
  int ksb = g >> 4, cb = g & 15;
  int cg = tid & 15, rgr = tid >> 4;
  int c0 = cb * 64 + cg * 4;
  int m0 = rh * 64;
  int seg = ksb >> 2;                 // constant per block
  const float4* f4 = (const float4*)fhid;
  float4 acc[4];
#pragma unroll
  for (int r = 0; r < 4; ++r) acc[r] = make_float4(0.f, 0.f, 0.f, 0.f);
  for (int kch = 0; kch < 4; ++kch) {
    int kg = ksb * 256 + kch * 64;
    int fb4 = (kg & 1023) >> 2;
    __syncthreads();
#pragma unroll
    for (int j = 0; j < 4; ++j) {
      int idx = tid + j * 256;           // 0..1023
      int r = idx >> 4, q = idx & 15;    // r 0..63
      int row = m0 + r;
      float4 uv;
      if (seg == 0) uv = f4[row * 256 + fb4 + q];
      else if (seg == 1) uv = f4[(128 + row) * 256 + fb4 + q];
      else {
        float4 f1v = f4[row * 256 + fb4 + q];
        float4 f2v = f4[(128 + row) * 256 + fb4 + q];
        if (seg == 2)
          uv = make_float4(fabsf(f1v.x - f2v.x), fabsf(f1v.y - f2v.y),
                           fabsf(f1v.z - f2v.z), fabsf(f1v.w - f2v.w));
        else
          uv = make_float4(f1v.x * f2v.x, f1v.y * f2v.y,
                           f1v.z * f2v.z, f1v.w * f2v.w);
      }
      *(float4*)&ush[r * APAD + q * 4] = uv;
    }
    __syncthreads();
    const float* Wp = W1 + (size_t)kg * HDIM + c0;
    float4 w[4];
#pragma unroll
    for (int j = 0; j < 4; ++j) w[j] = *(const float4*)(Wp + (size_t)j * HDIM);
#pragma unroll
    for (int kk = 0; kk < 64; kk += 4) {
      float4 wn[4];
      if (kk + 4 < 64) {
#pragma unroll
        for (int j = 0; j < 4; ++j)
          wn[j] = *(const float4*)(Wp + (size_t)(kk + 4 + j) * HDIM);
      }
#pragma unroll
      for (int r = 0; r < 4; ++r) {
        float4 a = *(const float4*)&ush[(rgr + 16 * r) * APAD + kk];
        fma4(acc[r], a.x, w[0]); fma4(acc[r], a.y, w[1]);
        fma4(acc[r], a.z, w[2]); fma4(acc[r], a.w, w[3]);
      }
#pragma unroll
      for (int j = 0; j < 4; ++j) w[j] = wn[j];
    }
  }
  float* dst = part + ((size_t)ksb * 128 + m0 + rgr) * HDIM + c0;
#pragma unroll
  for (int r = 0; r < 4; ++r)
    *(float4*)(dst + (size_t)r * 16 * HDIM) = acc[r];
}

// K_E: blocks 0..127 = classifier for batch b (float4 reduce, direct store);
//      block 128 = dis/diff finals.  [round-0 code; NKS=16]
extern "C" __global__ __launch_bounds__(256)
void k_clf_final(const float* __restrict__ part, const float* __restrict__ b1,
                 const float* __restrict__ W2, const float* __restrict__ b2,
                 const float* __restrict__ delta, const float* __restrict__ diffb,
                 float* __restrict__ out) {
  int blk = blockIdx.x, tid = threadIdx.x;
  __shared__ float red[768];
  if (blk == 128) {
    for (int s = 0; s < 2; ++s) {
      float v = 0.f, w = 0.f;
      if (tid < BB) { float d = delta[s * BB + tid]; v = d * d; w = diffb[s * BB + tid]; }
      red[tid] = v; __syncthreads();
      for (int off = 128; off; off >>= 1) { if (tid < off) red[tid] += red[tid + off]; __syncthreads(); }
      if (tid == 0) out[384 + s] = sqrtf(red[0]) / (float)BB;
      __syncthreads();
      red[tid] = w; __syncthreads();
      for (int off = 128; off; off >>= 1) { if (tid < off) red[tid] += red[tid + off]; __syncthreads(); }
      if (tid == 0) out[386 + s] = red[0] / (float)BB;
      __syncthreads();
    }
    return;
  }
  int b = blk;
  float4 p = ((const float4*)b1)[tid];
  const float4* p4 = (const float4*)part;
#pragma unroll
  for (int ks = 0; ks < NKS; ++ks) {
    float4 q = p4[((size_t)ks * 128 + b) * 256 + tid];
    p.x += q.x; p.y += q.y; p.z += q.z; p.w += q.w;
  }
  p.x = fmaxf(p.x, 0.f); p.y = fmaxf(p.y, 0.f);
  p.z = fmaxf(p.z, 0.f); p.w = fmaxf(p.w, 0.f);
  int k0 = tid * 4;
  float a0 = 0.f, a1 = 0.f, a2 = 0.f;
  a0 = fmaf(p.x, W2[(k0 + 0) * 3 + 0], a0); a1 = fmaf(p.x, W2[(k0 + 0) * 3 + 1], a1); a2 = fmaf(p.x, W2[(k0 + 0) * 3 + 2], a2);
  a0 = fmaf(p.y, W2[(k0 + 1) * 3 + 0], a0); a1 = fmaf(p.y, W2[(k0 + 1) * 3 + 1], a1); a2 = fmaf(p.y, W2[(k0 + 1) * 3 + 2], a2);
  a0 = fmaf(p.z, W2[(k0 + 2) * 3 + 0], a0); a1 = fmaf(p.z, W2[(k0 + 2) * 3 + 1], a1); a2 = fmaf(p.z, W2[(k0 + 2) * 3 + 2], a2);
  a0 = fmaf(p.w, W2[(k0 + 3) * 3 + 0], a0); a1 = fmaf(p.w, W2[(k0 + 3) * 3 + 1], a1); a2 = fmaf(p.w, W2[(k0 + 3) * 3 + 2], a2);
  red[tid] = a0; red[256 + tid] = a1; red[512 + tid] = a2;
  __syncthreads();
  for (int off = 128; off; off >>= 1) {
    if (tid < off) {
      red[tid] += red[tid + off];
      red[256 + tid] += red[256 + tid + off];
      red[512 + tid] += red[512 + tid + off];
    }
    __syncthreads();
  }
  if (tid == 0) {
    out[b * 3 + 0] = red[0]   + b2[0];
    out[b * 3 + 1] = red[256] + b2[1];
    out[b * 3 + 2] = red[512] + b2[2];
  }
}

extern "C" void kernel_launch(void* const* d_in, const int* in_sizes, int n_in,
                              void* d_out, int out_size, void* d_ws, size_t ws_size,
                              hipStream_t stream) {
  const int*   seq1  = (const int*)  d_in[0];
  const int*   seq2  = (const int*)  d_in[1];
  const float* emb   = (const float*)d_in[2];
  const float* W_top = (const float*)d_in[3];
  const float* b_top = (const float*)d_in[4];
  const float* W_act = (const float*)d_in[5];
  const float* b_act = (const float*)d_in[6];
  const float* W1    = (const float*)d_in[7];
  const float* b1    = (const float*)d_in[8];
  const float* W2    = (const float*)d_in[9];
  const float* b2    = (const float*)d_in[10];
  float* out = (float*)d_out;
  float* ws  = (float*)d_ws;

  float* Eact  = ws + WS_EACT;
  float* delta = ws + WS_DELTA;
  float* diffb = ws + WS_DIFFB;
  float* fhid  = ws + WS_FHID;
  float* bigb  = ws + WS_BIG;   // fpart, then reused as part

  hipLaunchKernelGGL(k_fh_eact,     dim3(256 + 8000), dim3(256), 0, stream, emb, W_top, W_act, seq1, seq2, bigb, Eact);
  hipLaunchKernelGGL(k_ftanh_stats, dim3(512),        dim3(256), 0, stream, bigb, b_top, seq1, seq2, Eact, b_act, fhid, delta, diffb);
  hipLaunchKernelGGL(k_part,        dim3(512),        dim3(256), 0, stream, fhid, W1, bigb);
  hipLaunchKernelGGL(k_clf_final,   dim3(129),        dim3(256), 0, stream, bigb, b1, W2, b2, delta, diffb, out);
}